// Round 9
// baseline (1433.852 us; speedup 1.0000x reference)
//
#include <hip/hip_runtime.h>
#include <stdint.h>
#include <stddef.h>

typedef _Float16 half_t;
typedef _Float16 half2_t __attribute__((ext_vector_type(2)));
typedef _Float16 half8_t __attribute__((ext_vector_type(8)));
typedef float    floatx4 __attribute__((ext_vector_type(4)));
typedef uint32_t u32x4   __attribute__((ext_vector_type(4)));
typedef int      intx4   __attribute__((ext_vector_type(4)));

#define SEQ_L 512
#define NBATCH 64
#define DIM 256
#define NTOT (NBATCH * SEQ_L)   // 32768 rows

// ---------- helpers ----------
__device__ __forceinline__ int dot4i8(uint32_t a, uint32_t b, int c) {
#if defined(__has_builtin)
#if __has_builtin(__builtin_amdgcn_sdot4)
  return __builtin_amdgcn_sdot4((int)a, (int)b, c, false);
#else
  int s = c;
  s += (int)(int8_t)(a)       * (int)(int8_t)(b);
  s += (int)(int8_t)(a >> 8)  * (int)(int8_t)(b >> 8);
  s += (int)(int8_t)(a >> 16) * (int)(int8_t)(b >> 16);
  s += (int)(int8_t)(a >> 24) * (int)(int8_t)(b >> 24);
  return s;
#endif
#else
  int s = c;
  s += (int)(int8_t)(a)       * (int)(int8_t)(b);
  s += (int)(int8_t)(a >> 8)  * (int)(int8_t)(b >> 8);
  s += (int)(int8_t)(a >> 16) * (int)(int8_t)(b >> 16);
  s += (int)(int8_t)(a >> 24) * (int)(int8_t)(b >> 24);
  return s;
#endif
}

__device__ __forceinline__ float sigmoidf_fast(float x) {
  return 1.0f / (1.0f + __expf(-x));
}
__device__ __forceinline__ float tanhf_fast(float x) {
  float e = __expf(2.0f * x);
  return 1.0f - 2.0f / (e + 1.0f);
}

// ---------- kernel 1: W -> f16, transposed to [768 n][256 k] ----------
__global__ void conv_w_kernel(const float* __restrict__ Wr,
                              const float* __restrict__ Wz,
                              const float* __restrict__ Wh,
                              half_t* __restrict__ Wt) {
  int n = blockIdx.x;          // 0..767
  int k = threadIdx.x;         // 0..255
  const float* W = (n < 256) ? Wr : ((n < 512) ? Wz : Wh);
  int j = n & 255;
  Wt[(size_t)n * DIM + k] = (half_t)W[(size_t)k * DIM + j];
}

// ---------- kernel 2: a = sigmoid(x@k1 - x@k2) per row ----------
__global__ __launch_bounds__(256) void attn_a_kernel(const float* __restrict__ inp,
                                                     const float* __restrict__ k1,
                                                     const float* __restrict__ k2,
                                                     float* __restrict__ a_arr) {
  int row  = blockIdx.x * 4 + (threadIdx.x >> 6);
  int lane = threadIdx.x & 63;
  const float4* x4 = (const float4*)(inp + (size_t)row * DIM);
  float4 xv  = x4[lane];
  float4 k1v = ((const float4*)k1)[lane];
  float4 k2v = ((const float4*)k2)[lane];
  float e1 = xv.x * k1v.x + xv.y * k1v.y + xv.z * k1v.z + xv.w * k1v.w;
  float e2 = xv.x * k2v.x + xv.y * k2v.y + xv.z * k2v.z + xv.w * k2v.w;
#pragma unroll
  for (int off = 32; off >= 1; off >>= 1) {
    e1 += __shfl_xor(e1, off);
    e2 += __shfl_xor(e2, off);
  }
  if (lane == 0) a_arr[row] = 1.0f / (1.0f + __expf(e2 - e1));
}

// ---------- kernel 2b: per-(gate,col) |U| max -> scale = max/127 ----------
__global__ __launch_bounds__(256) void uscale_kernel(const float* __restrict__ Ur,
                                                     const float* __restrict__ Uz,
                                                     const float* __restrict__ Uh,
                                                     float* __restrict__ su) {
  const int g = blockIdx.x;    // 0..2
  const int j = threadIdx.x;   // 0..255
  const float* U = (g == 0) ? Ur : ((g == 1) ? Uz : Uh);
  float m = 0.0f;
  for (int k = 0; k < DIM; ++k) m = fmaxf(m, fabsf(U[(size_t)k * DIM + j]));
  su[g * DIM + j] = fmaxf(m, 1e-30f) * (1.0f / 127.0f);
}

// ---------- kernel 2c: pack U -> i8 quads, STREAM layout ----------
// Stream layout for coalesced per-step refetch in recur:
//   chunk c = g*16 + (q>>2)  (c in 0..47)
//   Ust[(c*256 + j)*4 + (q&3)] = packed quad (g, q, col j)
// Lane j's 16B chunk sits at byte offset (c*256 + j)*16: consecutive lanes
// -> consecutive 16B => one fully-coalesced global_load_dwordx4 per chunk.
__global__ __launch_bounds__(256) void upack_kernel(const float* __restrict__ Ur,
                                                    const float* __restrict__ Uz,
                                                    const float* __restrict__ Uh,
                                                    const float* __restrict__ su,
                                                    uint32_t* __restrict__ Ust) {
  const int g = blockIdx.x;    // 0..2
  const int j = threadIdx.x;   // 0..255
  const float* U = (g == 0) ? Ur : ((g == 1) ? Uz : Uh);
  const float r = 1.0f / su[g * DIM + j];   // = 127/max
  for (int q = 0; q < 64; ++q) {
    uint32_t w = 0;
#pragma unroll
    for (int t = 0; t < 4; ++t) {
      float v = U[(size_t)(q * 4 + t) * DIM + j] * r;
      int mi = __float2int_rn(v);
      mi = mi < -127 ? -127 : (mi > 127 ? 127 : mi);
      w |= ((uint32_t)(mi & 0xFF)) << (8 * t);
    }
    const int c = g * 16 + (q >> 2);
    Ust[((size_t)c * 256 + j) * 4 + (q & 3)] = w;
  }
}

// ---------- kernel 3: P = X @ [Wr|Wz|Wh]  (MFMA f16, f32 acc, store f16) ----------
__global__ __launch_bounds__(256) void gemm_p_kernel(const float* __restrict__ X,
                                                     const half_t* __restrict__ Wt,
                                                     half_t* __restrict__ P) {
  __shared__ __align__(16) half_t As[128][32];
  __shared__ __align__(16) half_t Bs[128][32];
  const int tid  = threadIdx.x;
  const int bm   = blockIdx.x * 128;
  const int bn   = blockIdx.y * 128;
  const int lane = tid & 63;
  const int wave = tid >> 6;
  const int wm   = (wave >> 1) * 64;
  const int wn   = (wave & 1) * 64;
  const int quad = lane >> 4;
  const int l15  = lane & 15;
  const int r0   = tid >> 2;
  const int kc   = (tid & 3) * 8;

  floatx4 acc[4][4] = {};

  for (int k0 = 0; k0 < DIM; k0 += 32) {
#pragma unroll
    for (int hh = 0; hh < 2; ++hh) {
      int r = r0 + hh * 64;
      const float* asrc = X + (size_t)(bm + r) * DIM + k0 + kc;
      float4 f0 = *(const float4*)(asrc);
      float4 f1 = *(const float4*)(asrc + 4);
      half8_t av;
      av[0] = (half_t)f0.x; av[1] = (half_t)f0.y; av[2] = (half_t)f0.z; av[3] = (half_t)f0.w;
      av[4] = (half_t)f1.x; av[5] = (half_t)f1.y; av[6] = (half_t)f1.z; av[7] = (half_t)f1.w;
      *(half8_t*)(&As[r][kc]) = av;
      *(half8_t*)(&Bs[r][kc]) = *(const half8_t*)(Wt + (size_t)(bn + r) * DIM + k0 + kc);
    }
    __syncthreads();
    half8_t af[4], bf[4];
#pragma unroll
    for (int mi = 0; mi < 4; ++mi)
      af[mi] = *(const half8_t*)(&As[wm + mi * 16 + l15][quad * 8]);
#pragma unroll
    for (int ni = 0; ni < 4; ++ni)
      bf[ni] = *(const half8_t*)(&Bs[wn + ni * 16 + l15][quad * 8]);
#pragma unroll
    for (int mi = 0; mi < 4; ++mi)
#pragma unroll
      for (int ni = 0; ni < 4; ++ni)
        acc[mi][ni] = __builtin_amdgcn_mfma_f32_16x16x32_f16(af[mi], bf[ni], acc[mi][ni], 0, 0, 0);
    __syncthreads();
  }
#pragma unroll
  for (int mi = 0; mi < 4; ++mi)
#pragma unroll
    for (int ni = 0; ni < 4; ++ni) {
      int col = bn + wn + ni * 16 + l15;
#pragma unroll
      for (int rr = 0; rr < 4; ++rr) {
        int row = bm + wm + mi * 16 + quad * 4 + rr;
        P[(size_t)row * 768 + col] = (half_t)acc[mi][ni][rr];
      }
    }
}

// ---------- kernel 4: recurrence, 256 threads, U STREAMED from L2 ----------
// Round-9. Rounds 0-8 proved U can never be arch-VGPR-resident (allocator
// caps at ~132 regs regardless of launch bounds / waves_per_eu / pins) and
// every residency workaround pays a per-step AGPR shuttle. New approach:
// DON'T keep U resident. All 64 blocks read the SAME 192 KB of packed U ->
// one L2 copy per XCD, always hot. Per thread per step: 48 coalesced
// global_load_dwordx4 (1 KB/instr) re-fetch the whole window; 48-deep
// outstanding-load queue hides L2 latency under the 192 dots.
// Per-XCD BW: 8 blocks x 192 KB / step ~ 1.5 MB @ ~4.3 TB/s => ~860 cyc/step
// floor, vs r3's measured 2290 (shuttle-bound).
// The U base pointer is made opaque each iteration (empty "+v" asm) so the
// compiler cannot hoist the loop-invariant loads and re-create the
// residency disaster. Everything else = round-3 winner verbatim.
__global__ __launch_bounds__(256, 1) void recur_kernel(
    const half_t* __restrict__ P,     // [32768, 768] f16 (xWr | xWz | xWh)
    const float* __restrict__ a_arr,  // [32768]
    const int* __restrict__ cidx,     // [32768]
    const uint32_t* __restrict__ Ust, // [48][256][4] u32 stream-packed i8 quads
    const float* __restrict__ su,     // [3][256] scales (max/127)
    const float* __restrict__ br, const float* __restrict__ bz, const float* __restrict__ bh,
    float* __restrict__ out) {        // [32768, 256] f32
  const int j = threadIdx.x;          // 0..255 (column)

  __shared__ __align__(16) half_t   hist[SEQ_L][128];  // 128 KB (cols 128..255)
  __shared__ __align__(16) uint32_t mtb[2][64];        // 512 B dbuf mt (i8)

  const float scr = su[0 * DIM + j] * (1.0f / 127.0f);
  const float scz = su[1 * DIM + j] * (1.0f / 127.0f);
  const float sch = su[2 * DIM + j] * (1.0f / 127.0f);
  const float brj = br[j], bzj = bz[j], bhj = bh[j];

  // per-thread U stream base: chunk c lives at upv[c*256 + j]
  const u32x4* upv = (const u32x4*)Ust;

  // step 0 has mt == 0 (h0 = 0, c0 = 0)
  if (j < 64) mtb[0][j] = 0u;

  float mtj = 0.0f;                   // current step's mt[j] (f32, exact)
  const int base = blockIdx.x * SEQ_L;

  // ---- prefetch state for step 0 ----
  const half_t* prow0 = P + (size_t)base * 768;
  float pr_c = (float)prow0[j];
  float pz_c = (float)prow0[DIM + j];
  float ph_c = (float)prow0[2 * DIM + j];
  float a_n = a_arr[base + 1];
  int   c_n = cidx[base + 1];

  __syncthreads();   // publishes mtb[0]

  for (int i = 0; i < SEQ_L; ++i) {
    // ---- opaque U pointer: loads below cannot be hoisted/CSE'd across
    // iterations (would otherwise rebuild the 192-reg residency problem) ----
    asm volatile("" : "+v"(upv));

    // ---- coref prefetch for next step's mt: overlaps the dot phase ----
    const int  cp    = c_n - 1;          // <= i (valid coref constraint)
    const bool use_h = (cp == i);        // block-uniform
    float corefv = 0.0f;
    if (j >= 128) {                      // upper-half columns
      if (c_n > 0 && !use_h) corefv = (float)hist[cp][j - 128];
    }

    // ---- next-step global prefetch; consumed a full step later ----
    const int ip1 = (i + 1 < SEQ_L) ? (i + 1) : i;
    const half_t* prow = P + (size_t)(base + ip1) * 768;
    float pr_x = (float)prow[j];
    float pz_x = (float)prow[DIM + j];
    float ph_x = (float)prow[2 * DIM + j];
    const int ip2 = (i + 2 < SEQ_L) ? (i + 2) : (SEQ_L - 1);
    const float a_x = a_arr[base + ip2];
    const int   c_x = cidx[base + ip2];

    // ---- i8 dots over the FULL 256-element K; U streamed from L2 ----
    // chunk (g, cq): 4 u32 of U quads q = cq*4..cq*4+3, paired with mt
    // quad-group m4 = mtb words cq*4..cq*4+3. Bit-identical to r3's math.
    int ar = 0, az = 0, ah = 0;
    const u32x4* mq = (const u32x4*)(&mtb[i & 1][0]);
#pragma unroll
    for (int cq = 0; cq < 16; ++cq) {
      u32x4 m4 = mq[cq];                 // ds_read_b128, same-addr broadcast
      u32x4 u0 = upv[(0 * 16 + cq) * 256 + j];   // gate r chunk
      u32x4 u1 = upv[(1 * 16 + cq) * 256 + j];   // gate z chunk
      u32x4 u2 = upv[(2 * 16 + cq) * 256 + j];   // gate h chunk
      ar = dot4i8(m4.x, u0[0], ar);
      ar = dot4i8(m4.y, u0[1], ar);
      ar = dot4i8(m4.z, u0[2], ar);
      ar = dot4i8(m4.w, u0[3], ar);
      az = dot4i8(m4.x, u1[0], az);
      az = dot4i8(m4.y, u1[1], az);
      az = dot4i8(m4.z, u1[2], az);
      az = dot4i8(m4.w, u1[3], az);
      ah = dot4i8(m4.x, u2[0], ah);
      ah = dot4i8(m4.y, u2[1], ah);
      ah = dot4i8(m4.z, u2[2], ah);
      ah = dot4i8(m4.w, u2[3], ah);
    }

    const float fr = (float)ar * scr;
    const float fz = (float)az * scz;
    const float fh = (float)ah * sch;
    const float rg = sigmoidf_fast(pr_c + brj + fr);
    const float zg = sigmoidf_fast(pz_c + bzj + fz);
    const float hb = tanhf_fast(ph_c + bhj + rg * fh);
    const float h  = (1.0f - zg) * mtj + zg * hb;

    // ---- writes: direct out store (r3 behavior; ring measured worse) ----
    out[(size_t)(base + i) * DIM + j] = h;
    if (j >= 128) hist[i][j - 128] = (half_t)h;

    // ---- next step's mt (f32 exact for the recurrent path) ----
    float mtn;
    if (j < 128) {
      mtn = a_n * h;
    } else {
      const float coref = (c_n > 0) ? (use_h ? h : corefv) : 0.0f;
      mtn = (1.0f - a_n) * coref;
    }
    mtj = mtn;

    // ---- quantize + pack 4 columns' bytes -> one u32 (|mt| <= 1) ----
    int mi = __float2int_rn(mtn * 127.0f);
    mi = mi < -127 ? -127 : (mi > 127 ? 127 : mi);
    unsigned v0 = (unsigned)mi & 0xFFu;
    unsigned o1 = (unsigned)__shfl_xor((int)v0, 1) & 0xFFu;   // byte of col j^1
    unsigned pp = (j & 1) ? (o1 | (v0 << 8)) : (v0 | (o1 << 8));
    unsigned o2 = (unsigned)__shfl_xor((int)pp, 2);           // halfword of pair j^2
    unsigned qd = (j & 2) ? ((o2 & 0xFFFFu) | (pp << 16))
                          : ((pp & 0xFFFFu) | (o2 << 16));
    if ((j & 3) == 0) mtb[(i + 1) & 1][j >> 2] = qd;

    // rotate prefetch registers
    pr_c = pr_x; pz_c = pz_x; ph_c = ph_x;
    a_n = a_x;   c_n = c_x;

    // barrier: publishes mtb[(i+1)&1] + hist[i]; separates step-i reads of
    // mtb[i&1] from step-(i+1) writes into that buffer.
    __syncthreads();
  }
}

// ---------- launcher ----------
extern "C" void kernel_launch(void* const* d_in, const int* in_sizes, int n_in,
                              void* d_out, int out_size, void* d_ws, size_t ws_size,
                              hipStream_t stream) {
  const float* inp = (const float*)d_in[0];
  const int*   ci  = (const int*)d_in[1];
  const float* Wr  = (const float*)d_in[2];
  const float* br  = (const float*)d_in[3];
  const float* Ur  = (const float*)d_in[4];
  const float* Wz  = (const float*)d_in[5];
  const float* bz  = (const float*)d_in[6];
  const float* Uz  = (const float*)d_in[7];
  const float* Wh  = (const float*)d_in[8];
  const float* bh  = (const float*)d_in[9];
  const float* Uh  = (const float*)d_in[10];
  const float* k1  = (const float*)d_in[11];
  const float* k2  = (const float*)d_in[12];
  float* out = (float*)d_out;

  char* ws = (char*)d_ws;
  // ws carve: Wt f16 [768*256] | P f16 [32768*768] | a f32 [32768]
  //           | su f32 [3*256] | Ust u32 [48*256*4]
  half_t*   Wt    = (half_t*)ws;                               // 393216 B
  half_t*   P     = (half_t*)(ws + 393216);                    // 50331648 B
  float*    a_arr = (float*)(ws + 393216 + 50331648);          // 131072 B
  float*    su    = (float*)(ws + 50855936);                   // 3072 B
  uint32_t* Ust   = (uint32_t*)(ws + 50859008);                // 196608 B

  conv_w_kernel<<<dim3(768), dim3(256), 0, stream>>>(Wr, Wz, Wh, Wt);
  attn_a_kernel<<<dim3(NTOT / 4), dim3(256), 0, stream>>>(inp, k1, k2, a_arr);
  uscale_kernel<<<dim3(3), dim3(256), 0, stream>>>(Ur, Uz, Uh, su);
  upack_kernel<<<dim3(3), dim3(256), 0, stream>>>(Ur, Uz, Uh, su, Ust);
  gemm_p_kernel<<<dim3(NTOT / 128, 6), dim3(256), 0, stream>>>(inp, Wt, P);
  recur_kernel<<<dim3(NBATCH), dim3(256), 0, stream>>>(P, a_arr, ci, Ust, su,
                                                       br, bz, bh, out);
}

// Round 10
// 1419.006 us; speedup vs baseline: 1.0105x; 1.0105x over previous
//
#include <hip/hip_runtime.h>
#include <stdint.h>
#include <stddef.h>

typedef _Float16 half_t;
typedef _Float16 half2_t __attribute__((ext_vector_type(2)));
typedef _Float16 half8_t __attribute__((ext_vector_type(8)));
typedef float    floatx4 __attribute__((ext_vector_type(4)));
typedef uint32_t u32x4   __attribute__((ext_vector_type(4)));
typedef int      intx4   __attribute__((ext_vector_type(4)));

#define SEQ_L 512
#define NBATCH 64
#define DIM 256
#define NTOT (NBATCH * SEQ_L)   // 32768 rows

// ---------- helpers ----------
__device__ __forceinline__ float sigmoidf_fast(float x) {
  return 1.0f / (1.0f + __expf(-x));
}
__device__ __forceinline__ float tanhf_fast(float x) {
  float e = __expf(2.0f * x);
  return 1.0f - 2.0f / (e + 1.0f);
}

// ---------- kernel 1: W -> f16, transposed to [768 n][256 k] ----------
__global__ void conv_w_kernel(const float* __restrict__ Wr,
                              const float* __restrict__ Wz,
                              const float* __restrict__ Wh,
                              half_t* __restrict__ Wt) {
  int n = blockIdx.x;          // 0..767
  int k = threadIdx.x;         // 0..255
  const float* W = (n < 256) ? Wr : ((n < 512) ? Wz : Wh);
  int j = n & 255;
  Wt[(size_t)n * DIM + k] = (half_t)W[(size_t)k * DIM + j];
}

// ---------- kernel 2: a = sigmoid(x@k1 - x@k2) per row ----------
__global__ __launch_bounds__(256) void attn_a_kernel(const float* __restrict__ inp,
                                                     const float* __restrict__ k1,
                                                     const float* __restrict__ k2,
                                                     float* __restrict__ a_arr) {
  int row  = blockIdx.x * 4 + (threadIdx.x >> 6);
  int lane = threadIdx.x & 63;
  const float4* x4 = (const float4*)(inp + (size_t)row * DIM);
  float4 xv  = x4[lane];
  float4 k1v = ((const float4*)k1)[lane];
  float4 k2v = ((const float4*)k2)[lane];
  float e1 = xv.x * k1v.x + xv.y * k1v.y + xv.z * k1v.z + xv.w * k1v.w;
  float e2 = xv.x * k2v.x + xv.y * k2v.y + xv.z * k2v.z + xv.w * k2v.w;
#pragma unroll
  for (int off = 32; off >= 1; off >>= 1) {
    e1 += __shfl_xor(e1, off);
    e2 += __shfl_xor(e2, off);
  }
  if (lane == 0) a_arr[row] = 1.0f / (1.0f + __expf(e2 - e1));
}

// ---------- kernel 2b: per-(gate,col) |U| max -> scale = max/127 ----------
__global__ __launch_bounds__(256) void uscale_kernel(const float* __restrict__ Ur,
                                                     const float* __restrict__ Uz,
                                                     const float* __restrict__ Uh,
                                                     float* __restrict__ su) {
  const int g = blockIdx.x;    // 0..2
  const int j = threadIdx.x;   // 0..255
  const float* U = (g == 0) ? Ur : ((g == 1) ? Uz : Uh);
  float m = 0.0f;
  for (int k = 0; k < DIM; ++k) m = fmaxf(m, fabsf(U[(size_t)k * DIM + j]));
  su[g * DIM + j] = fmaxf(m, 1e-30f) * (1.0f / 127.0f);
}

// ---------- kernel 2c: pack U -> MFMA B-fragments ----------
// Bpack[(t*4 + kt)*64 + lane] = 16B (u32x4) B-operand fragment for output
// tile t (cols n = t*16 + (lane&15), n gate-major: g = n>>8, j = n&255)
// and K-tile kt (k = kt*64 + (lane>>4)*16 + byte 0..15).
// Standard CDNA B layout: col = lane&15, k-group = lane>>4 (16B each).
// Quantization identical to previous upack (round-to-nearest, clamp 127).
__global__ __launch_bounds__(64) void bpack_kernel(const float* __restrict__ Ur,
                                                   const float* __restrict__ Uz,
                                                   const float* __restrict__ Uh,
                                                   const float* __restrict__ su,
                                                   uint32_t* __restrict__ Bpack) {
  const int tk = blockIdx.x;     // 0..191 = t*4 + kt
  const int l  = threadIdx.x;    // 0..63
  const int t  = tk >> 2;
  const int kt = tk & 3;
  const int n  = t * 16 + (l & 15);   // 0..767
  const int g  = n >> 8;
  const int j  = n & 255;
  const float* U = (g == 0) ? Ur : ((g == 1) ? Uz : Uh);
  const float r = 1.0f / su[g * DIM + j];   // = 127/max
  const int k0 = kt * 64 + (l >> 4) * 16;
  u32x4 frag;
#pragma unroll
  for (int wi = 0; wi < 4; ++wi) {
    uint32_t w = 0;
#pragma unroll
    for (int b = 0; b < 4; ++b) {
      const int k = k0 + wi * 4 + b;
      float v = U[(size_t)k * DIM + j] * r;
      int mi = __float2int_rn(v);
      mi = mi < -127 ? -127 : (mi > 127 ? 127 : mi);
      w |= ((uint32_t)(mi & 0xFF)) << (8 * b);
    }
    frag[wi] = w;
  }
  ((u32x4*)Bpack)[(size_t)tk * 64 + l] = frag;
}

// ---------- kernel 3: P = X @ [Wr|Wz|Wh]  (MFMA f16, f32 acc, store f16) ----------
__global__ __launch_bounds__(256) void gemm_p_kernel(const float* __restrict__ X,
                                                     const half_t* __restrict__ Wt,
                                                     half_t* __restrict__ P) {
  __shared__ __align__(16) half_t As[128][32];
  __shared__ __align__(16) half_t Bs[128][32];
  const int tid  = threadIdx.x;
  const int bm   = blockIdx.x * 128;
  const int bn   = blockIdx.y * 128;
  const int lane = tid & 63;
  const int wave = tid >> 6;
  const int wm   = (wave >> 1) * 64;
  const int wn   = (wave & 1) * 64;
  const int quad = lane >> 4;
  const int l15  = lane & 15;
  const int r0   = tid >> 2;
  const int kc   = (tid & 3) * 8;

  floatx4 acc[4][4] = {};

  for (int k0 = 0; k0 < DIM; k0 += 32) {
#pragma unroll
    for (int hh = 0; hh < 2; ++hh) {
      int r = r0 + hh * 64;
      const float* asrc = X + (size_t)(bm + r) * DIM + k0 + kc;
      float4 f0 = *(const float4*)(asrc);
      float4 f1 = *(const float4*)(asrc + 4);
      half8_t av;
      av[0] = (half_t)f0.x; av[1] = (half_t)f0.y; av[2] = (half_t)f0.z; av[3] = (half_t)f0.w;
      av[4] = (half_t)f1.x; av[5] = (half_t)f1.y; av[6] = (half_t)f1.z; av[7] = (half_t)f1.w;
      *(half8_t*)(&As[r][kc]) = av;
      *(half8_t*)(&Bs[r][kc]) = *(const half8_t*)(Wt + (size_t)(bn + r) * DIM + k0 + kc);
    }
    __syncthreads();
    half8_t af[4], bf[4];
#pragma unroll
    for (int mi = 0; mi < 4; ++mi)
      af[mi] = *(const half8_t*)(&As[wm + mi * 16 + l15][quad * 8]);
#pragma unroll
    for (int ni = 0; ni < 4; ++ni)
      bf[ni] = *(const half8_t*)(&Bs[wn + ni * 16 + l15][quad * 8]);
#pragma unroll
    for (int mi = 0; mi < 4; ++mi)
#pragma unroll
      for (int ni = 0; ni < 4; ++ni)
        acc[mi][ni] = __builtin_amdgcn_mfma_f32_16x16x32_f16(af[mi], bf[ni], acc[mi][ni], 0, 0, 0);
    __syncthreads();
  }
#pragma unroll
  for (int mi = 0; mi < 4; ++mi)
#pragma unroll
    for (int ni = 0; ni < 4; ++ni) {
      int col = bn + wn + ni * 16 + l15;
#pragma unroll
      for (int rr = 0; rr < 4; ++rr) {
        int row = bm + wm + mi * 16 + quad * 4 + rr;
        P[(size_t)row * 768 + col] = (half_t)acc[mi][ni][rr];
      }
    }
}

// ---------- kernel 4: recurrence, 512 threads, MFMA i8 matvec ----------
// Round-10. r0-r9 exhausted the register file for U: not arch-resident
// (allocator caps ~132 regs; pins => AGPR round-trips), not AGPR-in-place
// (VOP3P can't source AGPRs), not streamed-to-VALU-dots (L2 latency serial
// at 1 wave/SIMD: r9 = 1270us). The matrix pipe is the one consumer that
// eats 1KB of operands per instruction without holding them:
//   Y[768] = U^T(256x768) . mt(256) as 48 col-tiles x 4 K-tiles of
//   v_mfma_i32_16x16x64_i8, 192 MFMA/step over 8 waves = 24/wave.
// A = mt broadcast to all 16 rows (every lane reads its k-group's 16B of
// mtb => all rows identical => immune to A row-mapping; C row0 = matvec).
// B = U streamed from L2 in fragment order (bpack), one coalesced dwordx4
// per lane per (tile,ktile); input-independent => prefetchable, and L2-hot
// (all 8 blocks/XCD read the same 192KB). Floor ~840 cyc/step (per-XCD L2
// BW) vs r3's measured 2290. Integer accumulation => bit-identical to the
// dot4 path (absmax must stay exactly 0.006347656).
// Phase 2 (gates/pack/out) = r3 verbatim on threads 0..255.
__global__ __launch_bounds__(512, 1) void recur_kernel(
    const half_t* __restrict__ P,      // [32768, 768] f16 (xWr | xWz | xWh)
    const float* __restrict__ a_arr,   // [32768]
    const int* __restrict__ cidx,      // [32768]
    const uint32_t* __restrict__ Bpack,// [192][64][4] u32 B-fragments
    const float* __restrict__ su,      // [3][256] scales (max/127)
    const float* __restrict__ br, const float* __restrict__ bz, const float* __restrict__ bh,
    float* __restrict__ out) {         // [32768, 256] f32
  const int tid  = threadIdx.x;        // 0..511
  const int wave = tid >> 6;           // 0..7
  const int lane = tid & 63;
  const int j    = tid;                // column, valid when tid < 256

  __shared__ __align__(16) half_t   hist[SEQ_L][128];  // 128 KB (cols 128..255)
  __shared__ __align__(16) int      part[768];         // 3 KB gate pre-acts (i32)
  __shared__ __align__(16) uint32_t mtb[2][64];        // 512 B dbuf mt (i8)

  // ---- gate-thread constants (tid < 256) ----
  float scr = 0.f, scz = 0.f, sch = 0.f, brj = 0.f, bzj = 0.f, bhj = 0.f;
  if (tid < 256) {
    scr = su[0 * DIM + j] * (1.0f / 127.0f);
    scz = su[1 * DIM + j] * (1.0f / 127.0f);
    sch = su[2 * DIM + j] * (1.0f / 127.0f);
    brj = br[j]; bzj = bz[j]; bhj = bh[j];
  }

  // step 0 has mt == 0 (h0 = 0, c0 = 0)
  if (tid < 64) mtb[0][tid] = 0u;

  float mtj = 0.0f;                    // current step's mt[j] (f32, exact)
  const int base = blockIdx.x * SEQ_L;

  // ---- prefetch state for step 0 (gate threads) ----
  float pr_c = 0.f, pz_c = 0.f, ph_c = 0.f, a_n = 0.f;
  int   c_n = 0;
  if (tid < 256) {
    const half_t* prow0 = P + (size_t)base * 768;
    pr_c = (float)prow0[j];
    pz_c = (float)prow0[DIM + j];
    ph_c = (float)prow0[2 * DIM + j];
    a_n = a_arr[base + 1];
    c_n = cidx[base + 1];
  }

  const int t0 = wave * 6;             // this wave's first output col-tile

  __syncthreads();   // publishes mtb[0]

  for (int i = 0; i < SEQ_L; ++i) {
    // ---- opaque B base: loads cannot be CSE'd/hoisted across steps ----
    const u32x4* bp = (const u32x4*)Bpack;
    asm volatile("" : "+v"(bp));

    // ---- gate-thread prefetches: overlap the MFMA phase ----
    int  cp = 0; bool use_h = false;
    float corefv = 0.f, pr_x = 0.f, pz_x = 0.f, ph_x = 0.f, a_x = 0.f;
    int   c_x = 0;
    if (tid < 256) {
      cp    = c_n - 1;                 // <= i (valid coref constraint)
      use_h = (cp == i);               // block-uniform
      if (j >= 128 && c_n > 0 && !use_h) corefv = (float)hist[cp][j - 128];
      const int ip1 = (i + 1 < SEQ_L) ? (i + 1) : i;
      const half_t* prow = P + (size_t)(base + ip1) * 768;
      pr_x = (float)prow[j];
      pz_x = (float)prow[DIM + j];
      ph_x = (float)prow[2 * DIM + j];
      const int ip2 = (i + 2 < SEQ_L) ? (i + 2) : (SEQ_L - 1);
      a_x = a_arr[base + ip2];
      c_x = cidx[base + ip2];
    }

    // ---- A fragments: mt k-tile kt, lane's k-group = (lane>>4)*16B ----
    const uint32_t* mw = &mtb[i & 1][0];
    intx4 afrag[4];
#pragma unroll
    for (int kt = 0; kt < 4; ++kt)
      afrag[kt] = *(const intx4*)(mw + kt * 16 + (lane >> 4) * 4);

    // ---- 6 output tiles x 4 K-tiles of MFMA; B streamed from L2 ----
    const intx4* bpi = (const intx4*)bp;
#pragma unroll
    for (int t = 0; t < 6; ++t) {
      intx4 acc = {0, 0, 0, 0};
#pragma unroll
      for (int kt = 0; kt < 4; ++kt) {
        intx4 bf = bpi[((size_t)((t0 + t) * 4 + kt)) * 64 + lane];
        acc = __builtin_amdgcn_mfma_i32_16x16x64_i8(afrag[kt], bf, acc, 0, 0, 0);
      }
      if (lane < 16) part[(t0 + t) * 16 + lane] = acc[0];   // C row 0
    }
    __syncthreads();   // B1: part visible; mtb[i&1] fully consumed

    // ---- gate phase (threads 0..255) — r3 math verbatim, bit-identical ----
    if (tid < 256) {
      const int ar = part[j];
      const int az = part[256 + j];
      const int ah = part[512 + j];
      const float fr = (float)ar * scr;
      const float fz = (float)az * scz;
      const float fh = (float)ah * sch;
      const float rg = sigmoidf_fast(pr_c + brj + fr);
      const float zg = sigmoidf_fast(pz_c + bzj + fz);
      const float hb = tanhf_fast(ph_c + bhj + rg * fh);
      const float h  = (1.0f - zg) * mtj + zg * hb;

      out[(size_t)(base + i) * DIM + j] = h;
      if (j >= 128) hist[i][j - 128] = (half_t)h;

      float mtn;
      if (j < 128) {
        mtn = a_n * h;
      } else {
        const float coref = (c_n > 0) ? (use_h ? h : corefv) : 0.0f;
        mtn = (1.0f - a_n) * coref;
      }
      mtj = mtn;

      int mi = __float2int_rn(mtn * 127.0f);
      mi = mi < -127 ? -127 : (mi > 127 ? 127 : mi);
      unsigned v0 = (unsigned)mi & 0xFFu;
      unsigned o1 = (unsigned)__shfl_xor((int)v0, 1) & 0xFFu;   // byte of col j^1
      unsigned pp = (j & 1) ? (o1 | (v0 << 8)) : (v0 | (o1 << 8));
      unsigned o2 = (unsigned)__shfl_xor((int)pp, 2);           // halfword of pair j^2
      unsigned qd = (j & 2) ? ((o2 & 0xFFFFu) | (pp << 16))
                            : ((pp & 0xFFFFu) | (o2 << 16));
      if ((j & 3) == 0) mtb[(i + 1) & 1][j >> 2] = qd;

      pr_c = pr_x; pz_c = pz_x; ph_c = ph_x;
      a_n = a_x;   c_n = c_x;
    }

    // B2: publishes mtb[(i+1)&1] + hist[i]; separates next step's A-reads
    // and part-writes from this step's consumers.
    __syncthreads();
  }
}

// ---------- launcher ----------
extern "C" void kernel_launch(void* const* d_in, const int* in_sizes, int n_in,
                              void* d_out, int out_size, void* d_ws, size_t ws_size,
                              hipStream_t stream) {
  const float* inp = (const float*)d_in[0];
  const int*   ci  = (const int*)d_in[1];
  const float* Wr  = (const float*)d_in[2];
  const float* br  = (const float*)d_in[3];
  const float* Ur  = (const float*)d_in[4];
  const float* Wz  = (const float*)d_in[5];
  const float* bz  = (const float*)d_in[6];
  const float* Uz  = (const float*)d_in[7];
  const float* Wh  = (const float*)d_in[8];
  const float* bh  = (const float*)d_in[9];
  const float* Uh  = (const float*)d_in[10];
  const float* k1  = (const float*)d_in[11];
  const float* k2  = (const float*)d_in[12];
  float* out = (float*)d_out;

  char* ws = (char*)d_ws;
  // ws carve: Wt f16 [768*256] | P f16 [32768*768] | a f32 [32768]
  //           | su f32 [3*256] | Bpack u32 [192*64*4]
  half_t*   Wt    = (half_t*)ws;                               // 393216 B
  half_t*   P     = (half_t*)(ws + 393216);                    // 50331648 B
  float*    a_arr = (float*)(ws + 393216 + 50331648);          // 131072 B
  float*    su    = (float*)(ws + 50855936);                   // 3072 B
  uint32_t* Bpack = (uint32_t*)(ws + 50859008);                // 196608 B

  conv_w_kernel<<<dim3(768), dim3(256), 0, stream>>>(Wr, Wz, Wh, Wt);
  attn_a_kernel<<<dim3(NTOT / 4), dim3(256), 0, stream>>>(inp, k1, k2, a_arr);
  uscale_kernel<<<dim3(3), dim3(256), 0, stream>>>(Ur, Uz, Uh, su);
  bpack_kernel<<<dim3(192), dim3(64), 0, stream>>>(Ur, Uz, Uh, su, Bpack);
  gemm_p_kernel<<<dim3(NTOT / 128, 6), dim3(256), 0, stream>>>(inp, Wt, P);
  recur_kernel<<<dim3(NBATCH), dim3(512), 0, stream>>>(P, a_arr, ci, Bpack, su,
                                                       br, bz, bh, out);
}

// Round 11
// 762.742 us; speedup vs baseline: 1.8799x; 1.8604x over previous
//
#include <hip/hip_runtime.h>
#include <stdint.h>
#include <stddef.h>

typedef _Float16 half_t;
typedef _Float16 half2_t __attribute__((ext_vector_type(2)));
typedef _Float16 half8_t __attribute__((ext_vector_type(8)));
typedef float    floatx4 __attribute__((ext_vector_type(4)));
typedef uint32_t u32x4   __attribute__((ext_vector_type(4)));
typedef int      intx4   __attribute__((ext_vector_type(4)));

#define SEQ_L 512
#define NBATCH 64
#define DIM 256
#define NTOT (NBATCH * SEQ_L)   // 32768 rows

// ---------- helpers ----------
__device__ __forceinline__ int dot4i8(uint32_t a, uint32_t b, int c) {
#if defined(__has_builtin)
#if __has_builtin(__builtin_amdgcn_sdot4)
  return __builtin_amdgcn_sdot4((int)a, (int)b, c, false);
#else
  int s = c;
  s += (int)(int8_t)(a)       * (int)(int8_t)(b);
  s += (int)(int8_t)(a >> 8)  * (int)(int8_t)(b >> 8);
  s += (int)(int8_t)(a >> 16) * (int)(int8_t)(b >> 16);
  s += (int)(int8_t)(a >> 24) * (int)(int8_t)(b >> 24);
  return s;
#endif
#else
  int s = c;
  s += (int)(int8_t)(a)       * (int)(int8_t)(b);
  s += (int)(int8_t)(a >> 8)  * (int)(int8_t)(b >> 8);
  s += (int)(int8_t)(a >> 16) * (int)(int8_t)(b >> 16);
  s += (int)(int8_t)(a >> 24) * (int)(int8_t)(b >> 24);
  return s;
#endif
}

__device__ __forceinline__ float sigmoidf_fast(float x) {
  return 1.0f / (1.0f + __expf(-x));
}
__device__ __forceinline__ float tanhf_fast(float x) {
  float e = __expf(2.0f * x);
  return 1.0f - 2.0f / (e + 1.0f);
}

// ---------- kernel 1: W -> f16, transposed to [768 n][256 k] ----------
__global__ void conv_w_kernel(const float* __restrict__ Wr,
                              const float* __restrict__ Wz,
                              const float* __restrict__ Wh,
                              half_t* __restrict__ Wt) {
  int n = blockIdx.x;          // 0..767
  int k = threadIdx.x;         // 0..255
  const float* W = (n < 256) ? Wr : ((n < 512) ? Wz : Wh);
  int j = n & 255;
  Wt[(size_t)n * DIM + k] = (half_t)W[(size_t)k * DIM + j];
}

// ---------- kernel 2: a = sigmoid(x@k1 - x@k2) per row ----------
__global__ __launch_bounds__(256) void attn_a_kernel(const float* __restrict__ inp,
                                                     const float* __restrict__ k1,
                                                     const float* __restrict__ k2,
                                                     float* __restrict__ a_arr) {
  int row  = blockIdx.x * 4 + (threadIdx.x >> 6);
  int lane = threadIdx.x & 63;
  const float4* x4 = (const float4*)(inp + (size_t)row * DIM);
  float4 xv  = x4[lane];
  float4 k1v = ((const float4*)k1)[lane];
  float4 k2v = ((const float4*)k2)[lane];
  float e1 = xv.x * k1v.x + xv.y * k1v.y + xv.z * k1v.z + xv.w * k1v.w;
  float e2 = xv.x * k2v.x + xv.y * k2v.y + xv.z * k2v.z + xv.w * k2v.w;
#pragma unroll
  for (int off = 32; off >= 1; off >>= 1) {
    e1 += __shfl_xor(e1, off);
    e2 += __shfl_xor(e2, off);
  }
  if (lane == 0) a_arr[row] = 1.0f / (1.0f + __expf(e2 - e1));
}

// ---------- kernel 2b: per-(gate,col) |U| max -> scale = max/127 ----------
__global__ __launch_bounds__(256) void uscale_kernel(const float* __restrict__ Ur,
                                                     const float* __restrict__ Uz,
                                                     const float* __restrict__ Uh,
                                                     float* __restrict__ su) {
  const int g = blockIdx.x;    // 0..2
  const int j = threadIdx.x;   // 0..255
  const float* U = (g == 0) ? Ur : ((g == 1) ? Uz : Uh);
  float m = 0.0f;
  for (int k = 0; k < DIM; ++k) m = fmaxf(m, fabsf(U[(size_t)k * DIM + j]));
  su[g * DIM + j] = fmaxf(m, 1e-30f) * (1.0f / 127.0f);
}

// ---------- kernel 2c: pack U -> i8 quads, layout Ui8[g][quad=k/4][j] ----------
__global__ __launch_bounds__(256) void upack_kernel(const float* __restrict__ Ur,
                                                    const float* __restrict__ Uz,
                                                    const float* __restrict__ Uh,
                                                    const float* __restrict__ su,
                                                    uint32_t* __restrict__ Ui8) {
  const int g = blockIdx.x;    // 0..2
  const int j = threadIdx.x;   // 0..255
  const float* U = (g == 0) ? Ur : ((g == 1) ? Uz : Uh);
  const float r = 1.0f / su[g * DIM + j];   // = 127/max
  for (int q = 0; q < 64; ++q) {
    uint32_t w = 0;
#pragma unroll
    for (int t = 0; t < 4; ++t) {
      float v = U[(size_t)(q * 4 + t) * DIM + j] * r;
      int mi = __float2int_rn(v);
      mi = mi < -127 ? -127 : (mi > 127 ? 127 : mi);
      w |= ((uint32_t)(mi & 0xFF)) << (8 * t);
    }
    Ui8[((size_t)g * 64 + q) * DIM + j] = w;
  }
}

// ---------- kernel 3: P = X @ [Wr|Wz|Wh]  (MFMA f16, f32 acc, store f16) ----------
__global__ __launch_bounds__(256) void gemm_p_kernel(const float* __restrict__ X,
                                                     const half_t* __restrict__ Wt,
                                                     half_t* __restrict__ P) {
  __shared__ __align__(16) half_t As[128][32];
  __shared__ __align__(16) half_t Bs[128][32];
  const int tid  = threadIdx.x;
  const int bm   = blockIdx.x * 128;
  const int bn   = blockIdx.y * 128;
  const int lane = tid & 63;
  const int wave = tid >> 6;
  const int wm   = (wave >> 1) * 64;
  const int wn   = (wave & 1) * 64;
  const int quad = lane >> 4;
  const int l15  = lane & 15;
  const int r0   = tid >> 2;
  const int kc   = (tid & 3) * 8;

  floatx4 acc[4][4] = {};

  for (int k0 = 0; k0 < DIM; k0 += 32) {
#pragma unroll
    for (int hh = 0; hh < 2; ++hh) {
      int r = r0 + hh * 64;
      const float* asrc = X + (size_t)(bm + r) * DIM + k0 + kc;
      float4 f0 = *(const float4*)(asrc);
      float4 f1 = *(const float4*)(asrc + 4);
      half8_t av;
      av[0] = (half_t)f0.x; av[1] = (half_t)f0.y; av[2] = (half_t)f0.z; av[3] = (half_t)f0.w;
      av[4] = (half_t)f1.x; av[5] = (half_t)f1.y; av[6] = (half_t)f1.z; av[7] = (half_t)f1.w;
      *(half8_t*)(&As[r][kc]) = av;
      *(half8_t*)(&Bs[r][kc]) = *(const half8_t*)(Wt + (size_t)(bn + r) * DIM + k0 + kc);
    }
    __syncthreads();
    half8_t af[4], bf[4];
#pragma unroll
    for (int mi = 0; mi < 4; ++mi)
      af[mi] = *(const half8_t*)(&As[wm + mi * 16 + l15][quad * 8]);
#pragma unroll
    for (int ni = 0; ni < 4; ++ni)
      bf[ni] = *(const half8_t*)(&Bs[wn + ni * 16 + l15][quad * 8]);
#pragma unroll
    for (int mi = 0; mi < 4; ++mi)
#pragma unroll
      for (int ni = 0; ni < 4; ++ni)
        acc[mi][ni] = __builtin_amdgcn_mfma_f32_16x16x32_f16(af[mi], bf[ni], acc[mi][ni], 0, 0, 0);
    __syncthreads();
  }
#pragma unroll
  for (int mi = 0; mi < 4; ++mi)
#pragma unroll
    for (int ni = 0; ni < 4; ++ni) {
      int col = bn + wn + ni * 16 + l15;
#pragma unroll
      for (int rr = 0; rr < 4; ++rr) {
        int row = bm + wm + mi * 16 + quad * 4 + rr;
        P[(size_t)row * 768 + col] = (half_t)acc[mi][ni][rr];
      }
    }
}

// ---------- kernel 4: recurrence, 768 threads, ONE output column/thread ----------
// Round-11. r9/r10 proved per-CU load BW (~60 B/cyc) makes per-step U
// streaming a ~6100 cyc/step wall; the recurrence is step-serial, so U must
// be HELD. The allocator ledger (r0-r8) shows what it willingly holds in
// arch VGPRs: ~132 regs (r3: kept 132 of 192 wanted, parked the rest in
// AGPRs = the shuttle; pins make it worse, r5). The untried point: want
// only 64 u32/thread. 768 threads, thread t owns output column n=t
// (gate t>>8, col t&255): U/thread = 64 u32, natural pressure ~120 < 132
// comfort and < the ~170 cap at 3 waves/SIMD => no remat, no parking, NO
// PINS, no asm. Per-gate partials go through LDS part[768]; threads 0..255
// run the r3 gate phase verbatim. Dots use 4 partial accumulators + tree
// sum — integer, associative, bit-identical to r3 (absmax oracle
// 0.006347656). 12 waves (3/SIMD) also hide the ds_read/exp chains that
// r3 (1 wave/SIMD) ate raw.
__global__ __launch_bounds__(768, 1) void recur_kernel(
    const half_t* __restrict__ P,     // [32768, 768] f16 (xWr | xWz | xWh)
    const float* __restrict__ a_arr,  // [32768]
    const int* __restrict__ cidx,     // [32768]
    const uint32_t* __restrict__ Ui8, // [3][64][256] packed i8 quads
    const float* __restrict__ su,     // [3][256] scales (max/127)
    const float* __restrict__ br, const float* __restrict__ bz, const float* __restrict__ bh,
    float* __restrict__ out) {        // [32768, 256] f32
  const int tid = threadIdx.x;        // 0..767
  const int g   = tid >> 8;           // gate 0..2
  const int j   = tid & 255;          // column 0..255

  __shared__ __align__(16) half_t   hist[SEQ_L][128];  // 128 KB (cols 128..255)
  __shared__ __align__(16) int      part[768];         // 3 KB gate pre-acts (i32)
  __shared__ __align__(16) uint32_t mtb[2][64];        // 512 B dbuf mt (i8)

  // ---- this thread's U column: 64 u32 = 16 u32x4, plain loads, NO pins ----
  u32x4 u[16];
#pragma unroll
  for (int c8 = 0; c8 < 16; ++c8) {
#pragma unroll
    for (int t = 0; t < 4; ++t)
      u[c8][t] = Ui8[((size_t)g * 64 + c8 * 4 + t) * DIM + j];
  }

  // ---- gate-thread constants (tid < 256) ----
  float scr = 0.f, scz = 0.f, sch = 0.f, brj = 0.f, bzj = 0.f, bhj = 0.f;
  if (tid < 256) {
    scr = su[0 * DIM + j] * (1.0f / 127.0f);
    scz = su[1 * DIM + j] * (1.0f / 127.0f);
    sch = su[2 * DIM + j] * (1.0f / 127.0f);
    brj = br[j]; bzj = bz[j]; bhj = bh[j];
  }

  // step 0 has mt == 0 (h0 = 0, c0 = 0)
  if (tid < 64) mtb[0][tid] = 0u;

  float mtj = 0.0f;                   // gate thread j: current step's mt[j]
  const int base = blockIdx.x * SEQ_L;

  // ---- prefetch state for step 0 (gate threads) ----
  float pr_c = 0.f, pz_c = 0.f, ph_c = 0.f, a_n = 0.f;
  int   c_n = 0;
  if (tid < 256) {
    const half_t* prow0 = P + (size_t)base * 768;
    pr_c = (float)prow0[j];
    pz_c = (float)prow0[DIM + j];
    ph_c = (float)prow0[2 * DIM + j];
    a_n = a_arr[base + 1];
    c_n = cidx[base + 1];
  }

  __syncthreads();   // publishes mtb[0]

  for (int i = 0; i < SEQ_L; ++i) {
    // ---- gate-thread prefetches first: loads in flight during dot phase ----
    int  cp = 0; bool use_h = false;
    float corefv = 0.f, pr_x = 0.f, pz_x = 0.f, ph_x = 0.f, a_x = 0.f;
    int   c_x = 0;
    if (tid < 256) {
      cp    = c_n - 1;                 // <= i (valid coref constraint)
      use_h = (cp == i);               // block-uniform
      if (j >= 128 && c_n > 0 && !use_h) corefv = (float)hist[cp][j - 128];
      const int ip1 = (i + 1 < SEQ_L) ? (i + 1) : i;
      const half_t* prow = P + (size_t)(base + ip1) * 768;
      pr_x = (float)prow[j];
      pz_x = (float)prow[DIM + j];
      ph_x = (float)prow[2 * DIM + j];
      const int ip2 = (i + 2 < SEQ_L) ? (i + 2) : (SEQ_L - 1);
      a_x = a_arr[base + ip2];
      c_x = cidx[base + ip2];
    }

    // ---- dot phase: ALL 768 threads, own column, 64 quads of K ----
    // 4 partial accumulators break the serial dot4 chain; integer adds are
    // associative => tree sum is bit-identical to r3's serial order.
    const u32x4* mq = (const u32x4*)(&mtb[i & 1][0]);
    int s0 = 0, s1 = 0, s2 = 0, s3 = 0;
#pragma unroll
    for (int c8 = 0; c8 < 4; ++c8) {
      u32x4 m4 = mq[c8];               // ds_read_b128, same-addr broadcast
      s0 = dot4i8(m4.x, u[c8][0], s0);
      s0 = dot4i8(m4.y, u[c8][1], s0);
      s0 = dot4i8(m4.z, u[c8][2], s0);
      s0 = dot4i8(m4.w, u[c8][3], s0);
    }
#pragma unroll
    for (int c8 = 4; c8 < 8; ++c8) {
      u32x4 m4 = mq[c8];
      s1 = dot4i8(m4.x, u[c8][0], s1);
      s1 = dot4i8(m4.y, u[c8][1], s1);
      s1 = dot4i8(m4.z, u[c8][2], s1);
      s1 = dot4i8(m4.w, u[c8][3], s1);
    }
#pragma unroll
    for (int c8 = 8; c8 < 12; ++c8) {
      u32x4 m4 = mq[c8];
      s2 = dot4i8(m4.x, u[c8][0], s2);
      s2 = dot4i8(m4.y, u[c8][1], s2);
      s2 = dot4i8(m4.z, u[c8][2], s2);
      s2 = dot4i8(m4.w, u[c8][3], s2);
    }
#pragma unroll
    for (int c8 = 12; c8 < 16; ++c8) {
      u32x4 m4 = mq[c8];
      s3 = dot4i8(m4.x, u[c8][0], s3);
      s3 = dot4i8(m4.y, u[c8][1], s3);
      s3 = dot4i8(m4.z, u[c8][2], s3);
      s3 = dot4i8(m4.w, u[c8][3], s3);
    }
    part[tid] = (s0 + s1) + (s2 + s3);
    __syncthreads();   // B1: part visible; mtb[i&1] fully consumed

    // ---- gate phase (threads 0..255) — r3 math verbatim, bit-identical ----
    if (tid < 256) {
      const int ar = part[j];
      const int az = part[256 + j];
      const int ah = part[512 + j];
      const float fr = (float)ar * scr;
      const float fz = (float)az * scz;
      const float fh = (float)ah * sch;
      const float rg = sigmoidf_fast(pr_c + brj + fr);
      const float zg = sigmoidf_fast(pz_c + bzj + fz);
      const float hb = tanhf_fast(ph_c + bhj + rg * fh);
      const float h  = (1.0f - zg) * mtj + zg * hb;

      out[(size_t)(base + i) * DIM + j] = h;
      if (j >= 128) hist[i][j - 128] = (half_t)h;

      float mtn;
      if (j < 128) {
        mtn = a_n * h;
      } else {
        const float coref = (c_n > 0) ? (use_h ? h : corefv) : 0.0f;
        mtn = (1.0f - a_n) * coref;
      }
      mtj = mtn;

      int mi = __float2int_rn(mtn * 127.0f);
      mi = mi < -127 ? -127 : (mi > 127 ? 127 : mi);
      unsigned v0 = (unsigned)mi & 0xFFu;
      unsigned o1 = (unsigned)__shfl_xor((int)v0, 1) & 0xFFu;   // byte of col j^1
      unsigned pp = (j & 1) ? (o1 | (v0 << 8)) : (v0 | (o1 << 8));
      unsigned o2 = (unsigned)__shfl_xor((int)pp, 2);           // halfword of pair j^2
      unsigned qd = (j & 2) ? ((o2 & 0xFFFFu) | (pp << 16))
                            : ((pp & 0xFFFFu) | (o2 << 16));
      if ((j & 3) == 0) mtb[(i + 1) & 1][j >> 2] = qd;

      pr_c = pr_x; pz_c = pz_x; ph_c = ph_x;
      a_n = a_x;   c_n = c_x;
    }

    // B2: publishes mtb[(i+1)&1] + hist[i]; separates next step's mtb/part
    // accesses from this step's consumers.
    __syncthreads();
  }
}

// ---------- launcher ----------
extern "C" void kernel_launch(void* const* d_in, const int* in_sizes, int n_in,
                              void* d_out, int out_size, void* d_ws, size_t ws_size,
                              hipStream_t stream) {
  const float* inp = (const float*)d_in[0];
  const int*   ci  = (const int*)d_in[1];
  const float* Wr  = (const float*)d_in[2];
  const float* br  = (const float*)d_in[3];
  const float* Ur  = (const float*)d_in[4];
  const float* Wz  = (const float*)d_in[5];
  const float* bz  = (const float*)d_in[6];
  const float* Uz  = (const float*)d_in[7];
  const float* Wh  = (const float*)d_in[8];
  const float* bh  = (const float*)d_in[9];
  const float* Uh  = (const float*)d_in[10];
  const float* k1  = (const float*)d_in[11];
  const float* k2  = (const float*)d_in[12];
  float* out = (float*)d_out;

  char* ws = (char*)d_ws;
  // ws carve: Wt f16 [768*256] | P f16 [32768*768] | a f32 [32768]
  //           | su f32 [3*256] | Ui8 u32 [3*64*256]
  half_t*   Wt    = (half_t*)ws;                               // 393216 B
  half_t*   P     = (half_t*)(ws + 393216);                    // 50331648 B
  float*    a_arr = (float*)(ws + 393216 + 50331648);          // 131072 B
  float*    su    = (float*)(ws + 50855936);                   // 3072 B
  uint32_t* Ui8   = (uint32_t*)(ws + 50859008);                // 196608 B

  conv_w_kernel<<<dim3(768), dim3(256), 0, stream>>>(Wr, Wz, Wh, Wt);
  attn_a_kernel<<<dim3(NTOT / 4), dim3(256), 0, stream>>>(inp, k1, k2, a_arr);
  uscale_kernel<<<dim3(3), dim3(256), 0, stream>>>(Ur, Uz, Uh, su);
  upack_kernel<<<dim3(3), dim3(256), 0, stream>>>(Ur, Uz, Uh, su, Ui8);
  gemm_p_kernel<<<dim3(NTOT / 128, 6), dim3(256), 0, stream>>>(inp, Wt, P);
  recur_kernel<<<dim3(NBATCH), dim3(768), 0, stream>>>(P, a_arr, ci, Ui8, su,
                                                       br, bz, bh, out);
}